// Round 11
// baseline (254.325 us; speedup 1.0000x reference)
//
#include <hip/hip_runtime.h>

typedef __bf16 bf16;
typedef __bf16 bf16x2 __attribute__((ext_vector_type(2)));
typedef __bf16 bf16x4 __attribute__((ext_vector_type(4)));
typedef __bf16 bf16x8 __attribute__((ext_vector_type(8)));
typedef float f32x4 __attribute__((ext_vector_type(4)));

typedef __attribute__((address_space(1))) const void g_void;
typedef __attribute__((address_space(3))) void l_void;

constexpr int Bsz = 4, S = 2048, H = 512, NH = 8, DH = 64;
constexpr int M = Bsz * S;   // 8192 rows
constexpr int K = H;         // 512 reduction dim
constexpr int WELEM = H * H; // 262144 elems per weight matrix
constexpr float LOG2E  = 1.44269504f;
constexpr float QSCALE = 0.125f * LOG2E;  // fold 1/sqrt(DH)*log2e into q

// ---------------------------------------------------------------------------
// prep: fused convert_w (4 weights fp32->bf16) + scale_mask + ln1.
// NOTE (R9 lesson): do NOT fuse consumers across blocks with device fences —
// on 8-XCD gfx950 the required L2 writeback/invalidate costs >100us.
// Kernel boundaries are the cheap device-wide barrier.
// ---------------------------------------------------------------------------
__global__ __launch_bounds__(256) void prep(
    const float* __restrict__ hidden, const float* __restrict__ ln1_g,
    const float* __restrict__ ln1_b,
    const float* __restrict__ w0, const float* __restrict__ w1,
    const float* __restrict__ w2, const float* __restrict__ w3,
    const float* __restrict__ mask,
    bf16* __restrict__ h, bf16* __restrict__ wb, float* __restrict__ mask2) {
    int bx = blockIdx.x;
    int t = threadIdx.x;
    if (bx < M) {                        // ---- ln1: fp32 -> bf16, row = bx
        int row = bx;
        float2 xv = *(const float2*)(hidden + (size_t)row * H + t * 2);
        float v0 = xv.x, v1 = xv.y;
        float s = v0 + v1, s2 = v0 * v0 + v1 * v1;
        for (int off = 1; off < 64; off <<= 1) {
            s  += __shfl_xor(s,  off, 64);
            s2 += __shfl_xor(s2, off, 64);
        }
        __shared__ float red[8];
        int wid = t >> 6;
        if ((t & 63) == 0) { red[wid * 2] = s; red[wid * 2 + 1] = s2; }
        __syncthreads();
        s  = red[0] + red[2] + red[4] + red[6];
        s2 = red[1] + red[3] + red[5] + red[7];
        float mu  = s * (1.0f / H);
        float var = s2 * (1.0f / H) - mu * mu;
        float inv = rsqrtf(var + 1e-12f);
        float2 gv = *(const float2*)(ln1_g + t * 2);
        float2 bv = *(const float2*)(ln1_b + t * 2);
        bf16x2 out;
        out.x = (bf16)((v0 - mu) * inv * gv.x + bv.x);
        out.y = (bf16)((v1 - mu) * inv * gv.y + bv.y);
        *(bf16x2*)(h + (size_t)row * H + t * 2) = out;
    } else if (bx < M + 1024) {          // ---- convert_w
        int idx = bx - M;
        int y = idx >> 8, xx = idx & 255;
        const float* src = (y == 0) ? w0 : (y == 1) ? w1 : (y == 2) ? w2 : w3;
        bf16* d = wb + (size_t)y * WELEM;
        int i = (xx * 256 + t) * 4;
        float4 v = *(const float4*)(src + i);
        bf16x4 o;
        o.x = (bf16)v.x; o.y = (bf16)v.y; o.z = (bf16)v.z; o.w = (bf16)v.w;
        *(bf16x4*)(d + i) = o;
    } else {                             // ---- scale_mask
        int i = (bx - M - 1024) * 256 + t;
        mask2[i] = mask[i] * LOG2E;
    }
}

// LN2: bf16 in -> fp32 out.
__global__ __launch_bounds__(256) void ln_bf16_f32(
    const bf16* __restrict__ x, const float* __restrict__ g,
    const float* __restrict__ b, float* __restrict__ y) {
    int row = blockIdx.x;
    int t = threadIdx.x;
    bf16x2 xv = *(const bf16x2*)(x + (size_t)row * H + t * 2);
    float v0 = (float)xv.x, v1 = (float)xv.y;
    float s = v0 + v1, s2 = v0 * v0 + v1 * v1;
    for (int off = 1; off < 64; off <<= 1) {
        s  += __shfl_xor(s,  off, 64);
        s2 += __shfl_xor(s2, off, 64);
    }
    __shared__ float red[8];
    int wid = t >> 6;
    if ((t & 63) == 0) { red[wid * 2] = s; red[wid * 2 + 1] = s2; }
    __syncthreads();
    s  = red[0] + red[2] + red[4] + red[6];
    s2 = red[1] + red[3] + red[5] + red[7];
    float mu  = s * (1.0f / H);
    float var = s2 * (1.0f / H) - mu * mu;
    float inv = rsqrtf(var + 1e-12f);
    float2 gv = *(const float2*)(g + t * 2);
    float2 bv = *(const float2*)(b + t * 2);
    float2 out;
    out.x = (v0 - mu) * inv * gv.x + bv.x;
    out.y = (v1 - mu) * inv * gv.y + bv.y;
    *(float2*)(y + (size_t)row * H + t * 2) = out;
}

// ---------------------------------------------------------------------------
// 512-thread GEMM mainloop: C[BM x BN] tile of A[M,K]@W[N,K]^T.
// 8 waves (2 wm x 4 wn), per-wave (BM/2)x(BN/4) = MI x NI 16x16 frags.
// ---------------------------------------------------------------------------
template<int BM, int BN, int MI, int NI>
__device__ inline void gemm_mainloop512(const bf16* __restrict__ A,
                                        const bf16* __restrict__ W,
                                        int bm, int bn,
                                        bf16* As, bf16* Bs, f32x4 acc[MI][NI]) {
    int t = threadIdx.x;
    int lane = t & 63, wid = t >> 6;     // 8 waves
    int quad = lane >> 4, n = lane & 15;
    int wm = wid & 1, wn = wid >> 1;     // 2 x 4 wave grid
    int sw = (n & 7) * 8;                // frag-read xor (row&7)*8, row%8==n%8
    int srow = lane >> 3;                // staging: row within 8-row chunk
    int scol = (lane & 7) * 8;           // staging: col base (elems)
    constexpr int APW = BM / 64;         // A 8-row chunks per wave
    constexpr int BPW = BN / 64;
    constexpr int RM = MI * 16;          // rows per wm step
    constexpr int RN = NI * 16;          // cols per wn step
    for (int kt = 0; kt < K; kt += 64) {
        __syncthreads();                 // prior tile's readers done
        #pragma unroll
        for (int i = 0; i < APW; i++) {
            int chunk = wid * APW + i;   // wave-uniform
            int row = chunk * 8 + srow;
            int csrc = scol ^ ((row & 7) * 8);
            __builtin_amdgcn_global_load_lds(
                (g_void*)&A[(size_t)(bm + row) * K + kt + csrc],
                (l_void*)&As[chunk * 512], 16, 0, 0);
        }
        #pragma unroll
        for (int i = 0; i < BPW; i++) {
            int chunk = wid * BPW + i;
            int row = chunk * 8 + srow;
            int csrc = scol ^ ((row & 7) * 8);
            __builtin_amdgcn_global_load_lds(
                (g_void*)&W[(size_t)(bn + row) * K + kt + csrc],
                (l_void*)&Bs[chunk * 512], 16, 0, 0);
        }
        __syncthreads();                 // drains vmcnt(0) before compute
        #pragma unroll
        for (int half = 0; half < 2; half++) {
            bf16x8 af[MI], bfr[NI];
            int c = (half * 32 + quad * 8) ^ sw;
            #pragma unroll
            for (int mi = 0; mi < MI; mi++)
                af[mi] = *(const bf16x8*)&As[(wm * RM + mi * 16 + n) * 64 + c];
            #pragma unroll
            for (int ni = 0; ni < NI; ni++)
                bfr[ni] = *(const bf16x8*)&Bs[(wn * RN + ni * 16 + n) * 64 + c];
            #pragma unroll
            for (int mi = 0; mi < MI; mi++)
                #pragma unroll
                for (int ni = 0; ni < NI; ni++)
                    acc[mi][ni] = __builtin_amdgcn_mfma_f32_16x16x32_bf16(
                        af[mi], bfr[ni], acc[mi][ni], 0, 0, 0);
        }
    }
}

// QKV projection (R7 proven config). grid = (M/128, H/128, 3), 512 thr.
// z=0:q (QSCALE), z=1:k ([B,NH,S,DH]), z=2: v^T [B,NH,DH,S] via LDS transpose.
__global__ __launch_bounds__(512, 4) void gemm_qkv(
    const bf16* __restrict__ h, const bf16* __restrict__ wb,
    const float* __restrict__ bq, const float* __restrict__ bk,
    const float* __restrict__ bv,
    bf16* __restrict__ qd, bf16* __restrict__ kd, bf16* __restrict__ vtd) {
    __shared__ alignas(16) bf16 smem[17408];   // 34.8KB: As+Bs | T[128][136]
    bf16* As = smem;
    bf16* Bs = smem + 8192;
    int bm = blockIdx.x * 128, bn = blockIdx.y * 128, z = blockIdx.z;
    const bf16* W = wb + (size_t)z * WELEM;
    const float* bias = (z == 0) ? bq : (z == 1) ? bk : bv;
    f32x4 acc[4][2];
    for (int mi = 0; mi < 4; mi++)
        for (int ni = 0; ni < 2; ni++)
            for (int r = 0; r < 4; r++) acc[mi][ni][r] = 0.0f;
    gemm_mainloop512<128, 128, 4, 2>(h, W, bm, bn, As, Bs, acc);
    int t = threadIdx.x;
    int lane = t & 63, wid = t >> 6;
    int quad = lane >> 4, n = lane & 15;
    int wm = wid & 1, wn = wid >> 1;
    if (z < 2) {
        bf16* dst = (z == 0) ? qd : kd;
        for (int mi = 0; mi < 4; mi++)
            for (int ni = 0; ni < 2; ni++)
                for (int r = 0; r < 4; r++) {
                    int i = bm + wm * 64 + mi * 16 + quad * 4 + r;
                    int j = bn + wn * 32 + ni * 16 + n;
                    float val = acc[mi][ni][r] + bias[j];
                    if (z == 0) val *= QSCALE;
                    int b = i >> 11, srow = i & (S - 1);
                    int nh = j >> 6, d = j & (DH - 1);
                    dst[(((size_t)(b * NH + nh)) * S + srow) * DH + d] = (bf16)val;
                }
    } else {
        __syncthreads();                 // all waves done reading As/Bs
        bf16* T = smem;                  // [128 j][136] transposed tile
        for (int mi = 0; mi < 4; mi++)
            for (int ni = 0; ni < 2; ni++)
                for (int r = 0; r < 4; r++) {
                    int il = wm * 64 + mi * 16 + quad * 4 + r;
                    int jl = wn * 32 + ni * 16 + n;
                    float val = acc[mi][ni][r] + bias[bn + jl];
                    T[jl * 136 + il] = (bf16)val;
                }
        __syncthreads();
        int b = bm >> 11, srow0 = bm & (S - 1);
        int c16 = t & 15;                // 16B chunk within d-row
        #pragma unroll
        for (int p = 0; p < 4; p++) {
            int jl = (t >> 4) + p * 32;
            int j = bn + jl;
            int nh = j >> 6, d = j & (DH - 1);
            bf16x8 v = *(const bf16x8*)&T[jl * 136 + c16 * 8];
            *(bf16x8*)&vtd[(((size_t)(b * NH + nh)) * DH + d) * S
                           + srow0 + c16 * 8] = v;
        }
    }
}

// Output projection + bias + residual(h) -> tmp (bf16, row-major [M,H]).
// BM=64 x BN=128, 512 thr, grid (128,4)=512 blocks = 1 exact pass.
__global__ __launch_bounds__(512, 4) void gemm_out(
    const bf16* __restrict__ ctx, const bf16* __restrict__ wo,
    const float* __restrict__ bo, const bf16* __restrict__ resid,
    bf16* __restrict__ dst) {
    __shared__ alignas(16) bf16 As[64 * 64];
    __shared__ alignas(16) bf16 Bs[128 * 64];
    int bm = blockIdx.x * 64, bn = blockIdx.y * 128;
    f32x4 acc[2][2];
    for (int mi = 0; mi < 2; mi++)
        for (int ni = 0; ni < 2; ni++)
            for (int r = 0; r < 4; r++) acc[mi][ni][r] = 0.0f;
    gemm_mainloop512<64, 128, 2, 2>(ctx, wo, bm, bn, As, Bs, acc);
    int lane = threadIdx.x & 63, wid = threadIdx.x >> 6;
    int quad = lane >> 4, n = lane & 15;
    int wm = wid & 1, wn = wid >> 1;
    for (int mi = 0; mi < 2; mi++)
        for (int ni = 0; ni < 2; ni++)
            for (int r = 0; r < 4; r++) {
                int i = bm + wm * 32 + mi * 16 + quad * 4 + r;
                int j = bn + wn * 32 + ni * 16 + n;
                float val = acc[mi][ni][r] + bo[j]
                          + (float)resid[(size_t)i * H + j];
                dst[(size_t)i * H + j] = (bf16)val;
            }
}

// ---------------------------------------------------------------------------
// Flash attention v11: barrier-free main loop. K and V fragments load
// DIRECTLY from global (K/V per (b,nh) = 512KB, L2-resident; fragment
// addresses are 16-row x 64B segments, well coalesced). With no K/V LDS
// staging there is no inter-wave sharing in the main loop -> ZERO barriers
// (Ps is per-wave); the compiler is free to software-pipeline loads across
// the unrolled body and kb iterations. This removes the 2x16 full-block
// vmcnt/lgkmcnt barrier drains that kept both pipes <40% busy in v10.
// Key-split (8 waves = 4 qg x 2 kh) and exp2 softmax (O,l pure sums;
// epilogue combine) unchanged from v9/v10. LDS: Ps only, 36.9KB.
// ---------------------------------------------------------------------------
constexpr int LDP9 = 72;    // P row stride (64 + 8 pad)

#if __has_builtin(__builtin_amdgcn_exp2f)
#define EXP2(x) __builtin_amdgcn_exp2f(x)
#else
#define EXP2(x) exp2f(x)
#endif

__global__ __launch_bounds__(512, 4) void attn_kernel(
    const bf16* __restrict__ q, const bf16* __restrict__ k,
    const bf16* __restrict__ vt, const float* __restrict__ mask2,
    bf16* __restrict__ ctx) {
    int bh = blockIdx.y;                 // b*NH + nh
    int b = bh >> 3, nh = bh & 7;
    int t = threadIdx.x, wid = t >> 6, lane = t & 63;
    int quad = lane >> 4, n = lane & 15;
    int qg = wid >> 1, kh = wid & 1;     // q-group, key-half
    int qbase = blockIdx.x * 128 + qg * 32;
    int kO = kh * 64;                    // this wave's key offset in tile

    const bf16* Qp = q  + (size_t)bh * S * DH;
    const bf16* Kp = k  + (size_t)bh * S * DH;
    const bf16* Vt = vt + (size_t)bh * DH * S;
    const float* mrow = mask2 + (size_t)b * S;   // pre-scaled by log2e

    __shared__ alignas(16) bf16 smem[18432];     // 36.9KB: Ps only
    bf16* Pw = smem + wid * (32 * LDP9);         // per-wave P^T [q][key]

    bf16x8 qf[2][2];
    #pragma unroll
    for (int qt = 0; qt < 2; qt++)
        #pragma unroll
        for (int hh = 0; hh < 2; hh++)
            qf[qt][hh] = *(const bf16x8*)
                &Qp[(size_t)(qbase + qt * 16 + n) * DH + hh * 32 + quad * 8];

    f32x4 O[2][4];
    #pragma unroll
    for (int qt = 0; qt < 2; qt++)
        for (int i = 0; i < 4; i++)
            for (int r = 0; r < 4; r++) O[qt][i][r] = 0.0f;
    float l_run[2] = {0.0f, 0.0f};

    for (int kb = 0; kb < S; kb += 128) {
        #pragma unroll
        for (int kt = 0; kt < 4; kt++) { // this wave's 64-key half
            const bf16* krg = &Kp[(size_t)(kb + kO + kt * 16 + n) * DH];
            bf16x8 ka = *(const bf16x8*)&krg[quad * 8];
            bf16x8 kc = *(const bf16x8*)&krg[32 + quad * 8];
            float4 mk = *(const float4*)&mrow[kb + kO + kt * 16 + quad * 4];
            #pragma unroll
            for (int qt = 0; qt < 2; qt++) {
                f32x4 s;
                for (int r = 0; r < 4; r++) s[r] = 0.0f;
                s = __builtin_amdgcn_mfma_f32_16x16x32_bf16(ka, qf[qt][0], s, 0, 0, 0);
                s = __builtin_amdgcn_mfma_f32_16x16x32_bf16(kc, qf[qt][1], s, 0, 0, 0);
                float p0 = EXP2(s[0] + mk.x);
                float p1 = EXP2(s[1] + mk.y);
                float p2 = EXP2(s[2] + mk.z);
                float p3 = EXP2(s[3] + mk.w);
                l_run[qt] += (p0 + p1) + (p2 + p3);
                bf16x4 w;
                w[0] = (bf16)p0; w[1] = (bf16)p1; w[2] = (bf16)p2; w[3] = (bf16)p3;
                *(bf16x4*)&Pw[(qt * 16 + n) * LDP9 + kt * 16 + quad * 4] = w;
            }
        }

        __builtin_amdgcn_s_setprio(1);
        #pragma unroll
        for (int ks = 0; ks < 2; ks++)
            #pragma unroll
            for (int qt = 0; qt < 2; qt++) {
                bf16x8 pf = *(const bf16x8*)
                    &Pw[(qt * 16 + n) * LDP9 + ks * 32 + quad * 8];
                #pragma unroll
                for (int dt = 0; dt < 4; dt++) {
                    bf16x8 vf = *(const bf16x8*)
                        &Vt[(size_t)(dt * 16 + n) * S
                            + kb + kO + ks * 32 + quad * 8];
                    O[qt][dt] = __builtin_amdgcn_mfma_f32_16x16x32_bf16(
                        vf, pf, O[qt][dt], 0, 0, 0);
                }
            }
        __builtin_amdgcn_s_setprio(0);
    }

    // --- combine key-half partials (O,l are pure sums) -------------------
    float* Ob = (float*)smem;            // [4 qg][32 q][68] fp32 (2-way banks)
    float* Lb = Ob + 4 * 32 * 68;        // [4 qg][2 qt][64 lanes]
    __syncthreads();                     // all waves done with Pw; smem reusable
    if (kh) {
        #pragma unroll
        for (int qt = 0; qt < 2; qt++) {
            #pragma unroll
            for (int dt = 0; dt < 4; dt++)
                *(f32x4*)&Ob[(qg * 32 + qt * 16 + n) * 68 + dt * 16 + quad * 4]
                    = O[qt][dt];
            Lb[(qg * 2 + qt) * 64 + lane] = l_run[qt];
        }
    }
    __syncthreads();
    if (!kh) {
        #pragma unroll
        for (int qt = 0; qt < 2; qt++) {
            float l = l_run[qt] + Lb[(qg * 2 + qt) * 64 + lane];
            l += __shfl_xor(l, 16, 64);
            l += __shfl_xor(l, 32, 64);
            float linv = 1.0f / l;
            int srow = qbase + qt * 16 + n;
            #pragma unroll
            for (int dt = 0; dt < 4; dt++) {
                f32x4 po = *(const f32x4*)
                    &Ob[(qg * 32 + qt * 16 + n) * 68 + dt * 16 + quad * 4];
                bf16x4 o4;
                for (int r = 0; r < 4; r++)
                    o4[r] = (bf16)((O[qt][dt][r] + po[r]) * linv);
                int col = nh * 64 + dt * 16 + quad * 4;
                *(bf16x4*)&ctx[((size_t)(b * S + srow)) * H + col] = o4;
            }
        }
    }
}

// ---------------------------------------------------------------------------
extern "C" void kernel_launch(void* const* d_in, const int* in_sizes, int n_in,
                              void* d_out, int out_size, void* d_ws, size_t ws_size,
                              hipStream_t stream) {
    const float* hidden = (const float*)d_in[0];
    const float* mask   = (const float*)d_in[1];
    const float* ln1_g  = (const float*)d_in[2];
    const float* ln1_b  = (const float*)d_in[3];
    const float* wq = (const float*)d_in[4],  *bq = (const float*)d_in[5];
    const float* wk = (const float*)d_in[6],  *bk = (const float*)d_in[7];
    const float* wv = (const float*)d_in[8],  *bv = (const float*)d_in[9];
    const float* wo = (const float*)d_in[10], *bo = (const float*)d_in[11];
    const float* ln2_g = (const float*)d_in[12];
    const float* ln2_b = (const float*)d_in[13];

    const size_t T = (size_t)M * H;     // 4M elems per activation tensor
    bf16* wb  = (bf16*)d_ws;            // 4 weights, bf16: 4*WELEM
    bf16* h   = wb  + (size_t)4 * WELEM;
    bf16* qd  = h   + T;
    bf16* kd  = qd  + T;
    bf16* vtd = kd  + T;
    bf16* ctx = vtd + T;
    float* mask2 = (float*)(ctx + T);   // B*S fp32, mask*log2e
    bf16* tmp = qd;                     // qd is dead after attn_kernel

    prep<<<M + 1024 + 32, 256, 0, stream>>>(
        hidden, ln1_g, ln1_b, wq, wk, wv, wo, mask, h, wb, mask2);
    gemm_qkv<<<dim3(M / 128, H / 128, 3), 512, 0, stream>>>(
        h, wb, bq, bk, bv, qd, kd, vtd);
    attn_kernel<<<dim3(S / 128, Bsz * NH), 512, 0, stream>>>(qd, kd, vtd, mask2, ctx);
    gemm_out<<<dim3(M / 64, H / 128), 512, 0, stream>>>(
        ctx, wb + (size_t)3 * WELEM, bo, h, tmp);
    ln_bf16_f32<<<M, 256, 0, stream>>>(tmp, ln2_g, ln2_b, (float*)d_out);
}

// Round 12
// 190.144 us; speedup vs baseline: 1.3375x; 1.3375x over previous
//
#include <hip/hip_runtime.h>

typedef __bf16 bf16;
typedef __bf16 bf16x2 __attribute__((ext_vector_type(2)));
typedef __bf16 bf16x4 __attribute__((ext_vector_type(4)));
typedef __bf16 bf16x8 __attribute__((ext_vector_type(8)));
typedef float f32x4 __attribute__((ext_vector_type(4)));

typedef __attribute__((address_space(1))) const void g_void;
typedef __attribute__((address_space(3))) void l_void;

constexpr int Bsz = 4, S = 2048, H = 512, NH = 8, DH = 64;
constexpr int M = Bsz * S;   // 8192 rows
constexpr int K = H;         // 512 reduction dim
constexpr int WELEM = H * H; // 262144 elems per weight matrix
constexpr float LOG2E  = 1.44269504f;
constexpr float QSCALE = 0.125f * LOG2E;  // fold 1/sqrt(DH)*log2e into q

// ---------------------------------------------------------------------------
// prep: fused convert_w (4 weights fp32->bf16) + scale_mask + ln1.
// NOTE (R9 lesson): do NOT fuse consumers across blocks with device fences —
// on 8-XCD gfx950 the required L2 writeback/invalidate costs >100us.
// Kernel boundaries are the cheap device-wide barrier.
// ---------------------------------------------------------------------------
__global__ __launch_bounds__(256) void prep(
    const float* __restrict__ hidden, const float* __restrict__ ln1_g,
    const float* __restrict__ ln1_b,
    const float* __restrict__ w0, const float* __restrict__ w1,
    const float* __restrict__ w2, const float* __restrict__ w3,
    const float* __restrict__ mask,
    bf16* __restrict__ h, bf16* __restrict__ wb, float* __restrict__ mask2) {
    int bx = blockIdx.x;
    int t = threadIdx.x;
    if (bx < M) {                        // ---- ln1: fp32 -> bf16, row = bx
        int row = bx;
        float2 xv = *(const float2*)(hidden + (size_t)row * H + t * 2);
        float v0 = xv.x, v1 = xv.y;
        float s = v0 + v1, s2 = v0 * v0 + v1 * v1;
        for (int off = 1; off < 64; off <<= 1) {
            s  += __shfl_xor(s,  off, 64);
            s2 += __shfl_xor(s2, off, 64);
        }
        __shared__ float red[8];
        int wid = t >> 6;
        if ((t & 63) == 0) { red[wid * 2] = s; red[wid * 2 + 1] = s2; }
        __syncthreads();
        s  = red[0] + red[2] + red[4] + red[6];
        s2 = red[1] + red[3] + red[5] + red[7];
        float mu  = s * (1.0f / H);
        float var = s2 * (1.0f / H) - mu * mu;
        float inv = rsqrtf(var + 1e-12f);
        float2 gv = *(const float2*)(ln1_g + t * 2);
        float2 bv = *(const float2*)(ln1_b + t * 2);
        bf16x2 out;
        out.x = (bf16)((v0 - mu) * inv * gv.x + bv.x);
        out.y = (bf16)((v1 - mu) * inv * gv.y + bv.y);
        *(bf16x2*)(h + (size_t)row * H + t * 2) = out;
    } else if (bx < M + 1024) {          // ---- convert_w
        int idx = bx - M;
        int y = idx >> 8, xx = idx & 255;
        const float* src = (y == 0) ? w0 : (y == 1) ? w1 : (y == 2) ? w2 : w3;
        bf16* d = wb + (size_t)y * WELEM;
        int i = (xx * 256 + t) * 4;
        float4 v = *(const float4*)(src + i);
        bf16x4 o;
        o.x = (bf16)v.x; o.y = (bf16)v.y; o.z = (bf16)v.z; o.w = (bf16)v.w;
        *(bf16x4*)(d + i) = o;
    } else {                             // ---- scale_mask
        int i = (bx - M - 1024) * 256 + t;
        mask2[i] = mask[i] * LOG2E;
    }
}

// ---------------------------------------------------------------------------
// 512-thread GEMM mainloop: C[BM x BN] tile of A[M,K]@W[N,K]^T.
// 8 waves (2 wm x 4 wn), per-wave (BM/2)x(BN/4) = MI x NI 16x16 frags.
// ---------------------------------------------------------------------------
template<int BM, int BN, int MI, int NI>
__device__ inline void gemm_mainloop512(const bf16* __restrict__ A,
                                        const bf16* __restrict__ W,
                                        int bm, int bn,
                                        bf16* As, bf16* Bs, f32x4 acc[MI][NI]) {
    int t = threadIdx.x;
    int lane = t & 63, wid = t >> 6;     // 8 waves
    int quad = lane >> 4, n = lane & 15;
    int wm = wid & 1, wn = wid >> 1;     // 2 x 4 wave grid
    int sw = (n & 7) * 8;                // frag-read xor (row&7)*8, row%8==n%8
    int srow = lane >> 3;                // staging: row within 8-row chunk
    int scol = (lane & 7) * 8;           // staging: col base (elems)
    constexpr int APW = BM / 64;         // A 8-row chunks per wave
    constexpr int BPW = BN / 64;
    constexpr int RM = MI * 16;          // rows per wm step
    constexpr int RN = NI * 16;          // cols per wn step
    for (int kt = 0; kt < K; kt += 64) {
        __syncthreads();                 // prior tile's readers done
        #pragma unroll
        for (int i = 0; i < APW; i++) {
            int chunk = wid * APW + i;   // wave-uniform
            int row = chunk * 8 + srow;
            int csrc = scol ^ ((row & 7) * 8);
            __builtin_amdgcn_global_load_lds(
                (g_void*)&A[(size_t)(bm + row) * K + kt + csrc],
                (l_void*)&As[chunk * 512], 16, 0, 0);
        }
        #pragma unroll
        for (int i = 0; i < BPW; i++) {
            int chunk = wid * BPW + i;
            int row = chunk * 8 + srow;
            int csrc = scol ^ ((row & 7) * 8);
            __builtin_amdgcn_global_load_lds(
                (g_void*)&W[(size_t)(bn + row) * K + kt + csrc],
                (l_void*)&Bs[chunk * 512], 16, 0, 0);
        }
        __syncthreads();                 // drains vmcnt(0) before compute
        #pragma unroll
        for (int half = 0; half < 2; half++) {
            bf16x8 af[MI], bfr[NI];
            int c = (half * 32 + quad * 8) ^ sw;
            #pragma unroll
            for (int mi = 0; mi < MI; mi++)
                af[mi] = *(const bf16x8*)&As[(wm * RM + mi * 16 + n) * 64 + c];
            #pragma unroll
            for (int ni = 0; ni < NI; ni++)
                bfr[ni] = *(const bf16x8*)&Bs[(wn * RN + ni * 16 + n) * 64 + c];
            #pragma unroll
            for (int mi = 0; mi < MI; mi++)
                #pragma unroll
                for (int ni = 0; ni < NI; ni++)
                    acc[mi][ni] = __builtin_amdgcn_mfma_f32_16x16x32_bf16(
                        af[mi], bfr[ni], acc[mi][ni], 0, 0, 0);
        }
    }
}

// QKV projection (R7 proven config). grid = (M/128, H/128, 3), 512 thr.
// z=0:q (QSCALE), z=1:k ([B,NH,S,DH]), z=2: v^T [B,NH,DH,S] via LDS transpose.
__global__ __launch_bounds__(512, 4) void gemm_qkv(
    const bf16* __restrict__ h, const bf16* __restrict__ wb,
    const float* __restrict__ bq, const float* __restrict__ bk,
    const float* __restrict__ bv,
    bf16* __restrict__ qd, bf16* __restrict__ kd, bf16* __restrict__ vtd) {
    __shared__ alignas(16) bf16 smem[17408];   // 34.8KB: As+Bs | T[128][136]
    bf16* As = smem;
    bf16* Bs = smem + 8192;
    int bm = blockIdx.x * 128, bn = blockIdx.y * 128, z = blockIdx.z;
    const bf16* W = wb + (size_t)z * WELEM;
    const float* bias = (z == 0) ? bq : (z == 1) ? bk : bv;
    f32x4 acc[4][2];
    for (int mi = 0; mi < 4; mi++)
        for (int ni = 0; ni < 2; ni++)
            for (int r = 0; r < 4; r++) acc[mi][ni][r] = 0.0f;
    gemm_mainloop512<128, 128, 4, 2>(h, W, bm, bn, As, Bs, acc);
    int t = threadIdx.x;
    int lane = t & 63, wid = t >> 6;
    int quad = lane >> 4, n = lane & 15;
    int wm = wid & 1, wn = wid >> 1;
    if (z < 2) {
        bf16* dst = (z == 0) ? qd : kd;
        for (int mi = 0; mi < 4; mi++)
            for (int ni = 0; ni < 2; ni++)
                for (int r = 0; r < 4; r++) {
                    int i = bm + wm * 64 + mi * 16 + quad * 4 + r;
                    int j = bn + wn * 32 + ni * 16 + n;
                    float val = acc[mi][ni][r] + bias[j];
                    if (z == 0) val *= QSCALE;
                    int b = i >> 11, srow = i & (S - 1);
                    int nh = j >> 6, d = j & (DH - 1);
                    dst[(((size_t)(b * NH + nh)) * S + srow) * DH + d] = (bf16)val;
                }
    } else {
        __syncthreads();                 // all waves done reading As/Bs
        bf16* T = smem;                  // [128 j][136] transposed tile
        for (int mi = 0; mi < 4; mi++)
            for (int ni = 0; ni < 2; ni++)
                for (int r = 0; r < 4; r++) {
                    int il = wm * 64 + mi * 16 + quad * 4 + r;
                    int jl = wn * 32 + ni * 16 + n;
                    float val = acc[mi][ni][r] + bias[bn + jl];
                    T[jl * 136 + il] = (bf16)val;
                }
        __syncthreads();
        int b = bm >> 11, srow0 = bm & (S - 1);
        int c16 = t & 15;                // 16B chunk within d-row
        #pragma unroll
        for (int p = 0; p < 4; p++) {
            int jl = (t >> 4) + p * 32;
            int j = bn + jl;
            int nh = j >> 6, d = j & (DH - 1);
            bf16x8 v = *(const bf16x8*)&T[jl * 136 + c16 * 8];
            *(bf16x8*)&vtd[(((size_t)(b * NH + nh)) * DH + d) * S
                           + srow0 + c16 * 8] = v;
        }
    }
}

// ---------------------------------------------------------------------------
// gemm_out_ln2: full-row blocks (BM=32, BN=512) so ln2 fuses IN-BLOCK —
// no cross-block fences (R9 lesson). grid = M/32 = 256 blocks, 512 thr,
// 8 waves (2 wm x 4 wn), MI=1 x NI=8. After the K-loop: C+bias+residual
// -> LDS fp32 [32][516], in-block 16-lane shuffle LN over the full 512-wide
// row, fp32 out directly. Kills the ln2 kernel + the 8MB tmp round-trip.
// LDS: As 4KB + Bs 64KB = 68KB (Cf fp32 66KB reuses it).
// ---------------------------------------------------------------------------
__global__ __launch_bounds__(512, 4) void gemm_out_ln2(
    const bf16* __restrict__ ctx, const bf16* __restrict__ wo,
    const float* __restrict__ bo, const bf16* __restrict__ resid,
    const float* __restrict__ g2, const float* __restrict__ b2,
    float* __restrict__ out) {
    __shared__ alignas(16) bf16 smem[34816];   // 69632B: As(2048)+Bs(32768)
    bf16* As = smem;
    bf16* Bs = smem + 2048;
    int bm = blockIdx.x * 32;
    int t = threadIdx.x;
    int lane = t & 63, wid = t >> 6;
    int quad = lane >> 4, n = lane & 15;
    int wm = wid & 1, wn = wid >> 1;     // 2 x 4
    int sw = (n & 7) * 8;
    int srow = lane >> 3;
    int scol = (lane & 7) * 8;
    f32x4 acc[8];
    #pragma unroll
    for (int ni = 0; ni < 8; ni++)
        for (int r = 0; r < 4; r++) acc[ni][r] = 0.0f;
    for (int kt = 0; kt < K; kt += 64) {
        __syncthreads();
        if (wid < 4) {                   // A: 4 chunks (32 rows), waves 0-3
            int chunk = wid;
            int row = chunk * 8 + srow;
            int csrc = scol ^ ((row & 7) * 8);
            __builtin_amdgcn_global_load_lds(
                (g_void*)&ctx[(size_t)(bm + row) * K + kt + csrc],
                (l_void*)&As[chunk * 512], 16, 0, 0);
        }
        #pragma unroll
        for (int i = 0; i < 8; i++) {    // W: 64 chunks (512 rows), 8/wave
            int chunk = wid * 8 + i;
            int row = chunk * 8 + srow;
            int csrc = scol ^ ((row & 7) * 8);
            __builtin_amdgcn_global_load_lds(
                (g_void*)&wo[(size_t)row * K + kt + csrc],
                (l_void*)&Bs[chunk * 512], 16, 0, 0);
        }
        __syncthreads();
        #pragma unroll
        for (int half = 0; half < 2; half++) {
            int c = (half * 32 + quad * 8) ^ sw;
            bf16x8 af = *(const bf16x8*)&As[(wm * 16 + n) * 64 + c];
            bf16x8 bfr[8];
            #pragma unroll
            for (int ni = 0; ni < 8; ni++)
                bfr[ni] = *(const bf16x8*)&Bs[(wn * 128 + ni * 16 + n) * 64 + c];
            #pragma unroll
            for (int ni = 0; ni < 8; ni++)
                acc[ni] = __builtin_amdgcn_mfma_f32_16x16x32_bf16(
                    af, bfr[ni], acc[ni], 0, 0, 0);
        }
    }
    // --- epilogue: C + bias + residual -> LDS fp32 [32][516] -------------
    __syncthreads();                     // done reading As/Bs this pass
    float* Cf = (float*)smem;            // 32*516*4 = 66048B <= 69632B
    #pragma unroll
    for (int ni = 0; ni < 8; ni++)
        #pragma unroll
        for (int r = 0; r < 4; r++) {
            int il = wm * 16 + quad * 4 + r;
            int j = wn * 128 + ni * 16 + n;
            float val = acc[ni][r] + bo[j]
                      + (float)resid[(size_t)(bm + il) * H + j];
            Cf[il * 516 + j] = val;
        }
    __syncthreads();
    // --- in-block ln2: row = t>>4 (0..31), 16 lanes x 32 strided cols ----
    int row = t >> 4, l16 = t & 15;
    float s = 0.0f, s2 = 0.0f;
    #pragma unroll
    for (int c = 0; c < 32; c++) {
        float v = Cf[row * 516 + l16 + 16 * c];
        s += v; s2 += v * v;
    }
    s  += __shfl_xor(s, 1, 64);  s2 += __shfl_xor(s2, 1, 64);
    s  += __shfl_xor(s, 2, 64);  s2 += __shfl_xor(s2, 2, 64);
    s  += __shfl_xor(s, 4, 64);  s2 += __shfl_xor(s2, 4, 64);
    s  += __shfl_xor(s, 8, 64);  s2 += __shfl_xor(s2, 8, 64);
    float mu  = s * (1.0f / H);
    float var = s2 * (1.0f / H) - mu * mu;
    float inv = rsqrtf(var + 1e-12f);
    float* orow = out + (size_t)(bm + row) * H;
    #pragma unroll
    for (int c = 0; c < 32; c++) {
        int col = l16 + 16 * c;
        float v = Cf[row * 516 + col];
        orow[col] = (v - mu) * inv * g2[col] + b2[col];
    }
}

// ---------------------------------------------------------------------------
// Flash attention v10 (PROVEN 57.5us — R8/R10): key-split waves + T14
// reg-staged pipelined K/V. 512 thr = 8 waves = 4 q-groups x 2 key-halves;
// each wave 32 q x 64 keys. Next tile's K/V loads issue right after the
// write-barrier, hiding HBM/L2 latency under a full iter of compute.
// R11 lesson: LDS staging is load-bearing for COALESCING (direct-global
// fragment reads shatter into 16 segments/inst -> 2.3x slower). Keep it.
// LDS: Ks 16KB + Vs 16KB + Ps 8x4.5KB = 68KB -> 2 blocks/CU (16 waves).
// ---------------------------------------------------------------------------
constexpr int LDP9 = 72;    // P row stride (64 + 8 pad)

#if __has_builtin(__builtin_amdgcn_exp2f)
#define EXP2(x) __builtin_amdgcn_exp2f(x)
#else
#define EXP2(x) exp2f(x)
#endif

__global__ __launch_bounds__(512, 4) void attn_kernel(
    const bf16* __restrict__ q, const bf16* __restrict__ k,
    const bf16* __restrict__ vt, const float* __restrict__ mask2,
    bf16* __restrict__ ctx) {
    int bh = blockIdx.y;                 // b*NH + nh
    int b = bh >> 3, nh = bh & 7;
    int t = threadIdx.x, wid = t >> 6, lane = t & 63;
    int quad = lane >> 4, n = lane & 15;
    int qg = wid >> 1, kh = wid & 1;     // q-group, key-half
    int qbase = blockIdx.x * 128 + qg * 32;
    int kO = kh * 64;                    // this wave's key offset in tile

    const bf16* Qp = q  + (size_t)bh * S * DH;
    const bf16* Kp = k  + (size_t)bh * S * DH;
    const bf16* Vt = vt + (size_t)bh * DH * S;
    const float* mrow = mask2 + (size_t)b * S;   // pre-scaled by log2e

    __shared__ alignas(16) bf16 smem[34816];     // 68KB
    bf16* Ks = smem;                     // [128 keys][64 d], swizzled
    bf16* Vs = smem + 8192;              // [64 d][128 keys], swizzled
    bf16* Pw = smem + 16384 + wid * (32 * LDP9); // per-wave P^T [q][key]

    int sw = (n & 7) * 8;                // frag-read xor

    // per-thread staging geometry (K: 512x16B units; V: 1024x16B units)
    int krow = t >> 3;
    int kcs  = ((t & 7) * 8) ^ ((krow & 7) * 8);     // swizzled col
    size_t koff = (size_t)krow * DH + kcs;           // + kb*DH per tile
    int vr0 = t >> 4,        vc0 = ((t & 15) * 8) ^ ((vr0 & 7) * 8);
    int vr1 = (t + 512) >> 4, vc1 = ((t & 15) * 8) ^ ((vr1 & 7) * 8);
    size_t voff0 = (size_t)vr0 * S + vc0;            // + kb per tile
    size_t voff1 = (size_t)vr1 * S + vc1;

    bf16x8 qf[2][2];
    #pragma unroll
    for (int qt = 0; qt < 2; qt++)
        #pragma unroll
        for (int hh = 0; hh < 2; hh++)
            qf[qt][hh] = *(const bf16x8*)
                &Qp[(size_t)(qbase + qt * 16 + n) * DH + hh * 32 + quad * 8];

    f32x4 O[2][4];
    #pragma unroll
    for (int qt = 0; qt < 2; qt++)
        for (int i = 0; i < 4; i++)
            for (int r = 0; r < 4; r++) O[qt][i][r] = 0.0f;
    float l_run[2] = {0.0f, 0.0f};

    // prologue: load tile 0 into regs
    uint4 kreg  = *(const uint4*)&Kp[koff];
    uint4 vreg0 = *(const uint4*)&Vt[voff0];
    uint4 vreg1 = *(const uint4*)&Vt[voff1];

    for (int kb = 0; kb < S; kb += 128) {
        __syncthreads();                 // prior tile's readers done
        *(uint4*)&Ks[(size_t)t * 8] = kreg;
        *(uint4*)&Vs[(size_t)t * 8] = vreg0;
        *(uint4*)&Vs[(size_t)(t + 512) * 8] = vreg1;
        __syncthreads();                 // tile visible to all waves

        if (kb + 128 < S) {              // issue next-tile loads; latency
            kreg  = *(const uint4*)&Kp[koff + (size_t)(kb + 128) * DH];
            vreg0 = *(const uint4*)&Vt[voff0 + (kb + 128)];
            vreg1 = *(const uint4*)&Vt[voff1 + (kb + 128)];
        }                                // hides under this iter's compute

        #pragma unroll
        for (int kt = 0; kt < 4; kt++) { // this wave's 64-key half
            const bf16* kr = &Ks[(kO + kt * 16 + n) * 64];
            bf16x8 ka = *(const bf16x8*)&kr[(quad * 8) ^ sw];
            bf16x8 kc = *(const bf16x8*)&kr[(32 + quad * 8) ^ sw];
            float4 mk = *(const float4*)&mrow[kb + kO + kt * 16 + quad * 4];
            #pragma unroll
            for (int qt = 0; qt < 2; qt++) {
                f32x4 s;
                for (int r = 0; r < 4; r++) s[r] = 0.0f;
                s = __builtin_amdgcn_mfma_f32_16x16x32_bf16(ka, qf[qt][0], s, 0, 0, 0);
                s = __builtin_amdgcn_mfma_f32_16x16x32_bf16(kc, qf[qt][1], s, 0, 0, 0);
                float p0 = EXP2(s[0] + mk.x);
                float p1 = EXP2(s[1] + mk.y);
                float p2 = EXP2(s[2] + mk.z);
                float p3 = EXP2(s[3] + mk.w);
                l_run[qt] += (p0 + p1) + (p2 + p3);
                bf16x4 w;
                w[0] = (bf16)p0; w[1] = (bf16)p1; w[2] = (bf16)p2; w[3] = (bf16)p3;
                *(bf16x4*)&Pw[(qt * 16 + n) * LDP9 + kt * 16 + quad * 4] = w;
            }
        }

        __builtin_amdgcn_s_setprio(1);
        #pragma unroll
        for (int ks = 0; ks < 2; ks++)
            #pragma unroll
            for (int qt = 0; qt < 2; qt++) {
                bf16x8 pf = *(const bf16x8*)
                    &Pw[(qt * 16 + n) * LDP9 + ks * 32 + quad * 8];
                #pragma unroll
                for (int dt = 0; dt < 4; dt++) {
                    bf16x8 vf = *(const bf16x8*)
                        &Vs[(dt * 16 + n) * 128 + ((kO + ks * 32 + quad * 8) ^ sw)];
                    O[qt][dt] = __builtin_amdgcn_mfma_f32_16x16x32_bf16(
                        vf, pf, O[qt][dt], 0, 0, 0);
                }
            }
        __builtin_amdgcn_s_setprio(0);
    }

    // --- combine key-half partials (O,l are pure sums) -------------------
    float* Ob = (float*)smem;            // [4 qg][32 q][68] fp32 (2-way banks)
    float* Lb = Ob + 4 * 32 * 68;        // [4 qg][2 qt][64 lanes]
    __syncthreads();                     // all compute done; smem reusable
    if (kh) {
        #pragma unroll
        for (int qt = 0; qt < 2; qt++) {
            #pragma unroll
            for (int dt = 0; dt < 4; dt++)
                *(f32x4*)&Ob[(qg * 32 + qt * 16 + n) * 68 + dt * 16 + quad * 4]
                    = O[qt][dt];
            Lb[(qg * 2 + qt) * 64 + lane] = l_run[qt];
        }
    }
    __syncthreads();
    if (!kh) {
        #pragma unroll
        for (int qt = 0; qt < 2; qt++) {
            float l = l_run[qt] + Lb[(qg * 2 + qt) * 64 + lane];
            l += __shfl_xor(l, 16, 64);
            l += __shfl_xor(l, 32, 64);
            float linv = 1.0f / l;
            int srow = qbase + qt * 16 + n;
            #pragma unroll
            for (int dt = 0; dt < 4; dt++) {
                f32x4 po = *(const f32x4*)
                    &Ob[(qg * 32 + qt * 16 + n) * 68 + dt * 16 + quad * 4];
                bf16x4 o4;
                for (int r = 0; r < 4; r++)
                    o4[r] = (bf16)((O[qt][dt][r] + po[r]) * linv);
                int col = nh * 64 + dt * 16 + quad * 4;
                *(bf16x4*)&ctx[((size_t)(b * S + srow)) * H + col] = o4;
            }
        }
    }
}

// ---------------------------------------------------------------------------
extern "C" void kernel_launch(void* const* d_in, const int* in_sizes, int n_in,
                              void* d_out, int out_size, void* d_ws, size_t ws_size,
                              hipStream_t stream) {
    const float* hidden = (const float*)d_in[0];
    const float* mask   = (const float*)d_in[1];
    const float* ln1_g  = (const float*)d_in[2];
    const float* ln1_b  = (const float*)d_in[3];
    const float* wq = (const float*)d_in[4],  *bq = (const float*)d_in[5];
    const float* wk = (const float*)d_in[6],  *bk = (const float*)d_in[7];
    const float* wv = (const float*)d_in[8],  *bv = (const float*)d_in[9];
    const float* wo = (const float*)d_in[10], *bo = (const float*)d_in[11];
    const float* ln2_g = (const float*)d_in[12];
    const float* ln2_b = (const float*)d_in[13];

    const size_t T = (size_t)M * H;     // 4M elems per activation tensor
    bf16* wb  = (bf16*)d_ws;            // 4 weights, bf16: 4*WELEM
    bf16* h   = wb  + (size_t)4 * WELEM;
    bf16* qd  = h   + T;
    bf16* kd  = qd  + T;
    bf16* vtd = kd  + T;
    bf16* ctx = vtd + T;
    float* mask2 = (float*)(ctx + T);   // B*S fp32, mask*log2e

    prep<<<M + 1024 + 32, 256, 0, stream>>>(
        hidden, ln1_g, ln1_b, wq, wk, wv, wo, mask, h, wb, mask2);
    gemm_qkv<<<dim3(M / 128, H / 128, 3), 512, 0, stream>>>(
        h, wb, bq, bk, bv, qd, kd, vtd);
    attn_kernel<<<dim3(S / 128, Bsz * NH), 512, 0, stream>>>(qd, kd, vtd, mask2, ctx);
    gemm_out_ln2<<<M / 32, 512, 0, stream>>>(
        ctx, wb + (size_t)3 * WELEM, bo, h, ln2_g, ln2_b, (float*)d_out);
}

// Round 14
// 179.156 us; speedup vs baseline: 1.4196x; 1.0613x over previous
//
#include <hip/hip_runtime.h>

typedef __bf16 bf16;
typedef __bf16 bf16x2 __attribute__((ext_vector_type(2)));
typedef __bf16 bf16x4 __attribute__((ext_vector_type(4)));
typedef __bf16 bf16x8 __attribute__((ext_vector_type(8)));
typedef float f32x4 __attribute__((ext_vector_type(4)));

typedef __attribute__((address_space(1))) const void g_void;
typedef __attribute__((address_space(3))) void l_void;

constexpr int Bsz = 4, S = 2048, H = 512, NH = 8, DH = 64;
constexpr int M = Bsz * S;   // 8192 rows
constexpr int K = H;         // 512 reduction dim
constexpr int WELEM = H * H; // 262144 elems per weight matrix
constexpr float LOG2E  = 1.44269504f;
constexpr float QSCALE = 0.125f * LOG2E;  // fold 1/sqrt(DH)*log2e into q

// ---------------------------------------------------------------------------
// prep: fused convert_w (4 weights fp32->bf16) + scale_mask + ln1.
// R9 lesson: no cross-block fence fusion (L2 writeback >100us on 8 XCDs).
// Kernel boundaries are the cheap device-wide barrier.
// ---------------------------------------------------------------------------
__global__ __launch_bounds__(256) void prep(
    const float* __restrict__ hidden, const float* __restrict__ ln1_g,
    const float* __restrict__ ln1_b,
    const float* __restrict__ w0, const float* __restrict__ w1,
    const float* __restrict__ w2, const float* __restrict__ w3,
    const float* __restrict__ mask,
    bf16* __restrict__ h, bf16* __restrict__ wb, float* __restrict__ mask2) {
    int bx = blockIdx.x;
    int t = threadIdx.x;
    if (bx < M) {                        // ---- ln1: fp32 -> bf16, row = bx
        int row = bx;
        float2 xv = *(const float2*)(hidden + (size_t)row * H + t * 2);
        float v0 = xv.x, v1 = xv.y;
        float s = v0 + v1, s2 = v0 * v0 + v1 * v1;
        for (int off = 1; off < 64; off <<= 1) {
            s  += __shfl_xor(s,  off, 64);
            s2 += __shfl_xor(s2, off, 64);
        }
        __shared__ float red[8];
        int wid = t >> 6;
        if ((t & 63) == 0) { red[wid * 2] = s; red[wid * 2 + 1] = s2; }
        __syncthreads();
        s  = red[0] + red[2] + red[4] + red[6];
        s2 = red[1] + red[3] + red[5] + red[7];
        float mu  = s * (1.0f / H);
        float var = s2 * (1.0f / H) - mu * mu;
        float inv = rsqrtf(var + 1e-12f);
        float2 gv = *(const float2*)(ln1_g + t * 2);
        float2 bv = *(const float2*)(ln1_b + t * 2);
        bf16x2 out;
        out.x = (bf16)((v0 - mu) * inv * gv.x + bv.x);
        out.y = (bf16)((v1 - mu) * inv * gv.y + bv.y);
        *(bf16x2*)(h + (size_t)row * H + t * 2) = out;
    } else if (bx < M + 1024) {          // ---- convert_w
        int idx = bx - M;
        int y = idx >> 8, xx = idx & 255;
        const float* src = (y == 0) ? w0 : (y == 1) ? w1 : (y == 2) ? w2 : w3;
        bf16* d = wb + (size_t)y * WELEM;
        int i = (xx * 256 + t) * 4;
        float4 v = *(const float4*)(src + i);
        bf16x4 o;
        o.x = (bf16)v.x; o.y = (bf16)v.y; o.z = (bf16)v.z; o.w = (bf16)v.w;
        *(bf16x4*)(d + i) = o;
    } else {                             // ---- scale_mask
        int i = (bx - M - 1024) * 256 + t;
        mask2[i] = mask[i] * LOG2E;
    }
}

// LN2: bf16 in -> fp32 out.
__global__ __launch_bounds__(256) void ln_bf16_f32(
    const bf16* __restrict__ x, const float* __restrict__ g,
    const float* __restrict__ b, float* __restrict__ y) {
    int row = blockIdx.x;
    int t = threadIdx.x;
    bf16x2 xv = *(const bf16x2*)(x + (size_t)row * H + t * 2);
    float v0 = (float)xv.x, v1 = (float)xv.y;
    float s = v0 + v1, s2 = v0 * v0 + v1 * v1;
    for (int off = 1; off < 64; off <<= 1) {
        s  += __shfl_xor(s,  off, 64);
        s2 += __shfl_xor(s2, off, 64);
    }
    __shared__ float red[8];
    int wid = t >> 6;
    if ((t & 63) == 0) { red[wid * 2] = s; red[wid * 2 + 1] = s2; }
    __syncthreads();
    s  = red[0] + red[2] + red[4] + red[6];
    s2 = red[1] + red[3] + red[5] + red[7];
    float mu  = s * (1.0f / H);
    float var = s2 * (1.0f / H) - mu * mu;
    float inv = rsqrtf(var + 1e-12f);
    float2 gv = *(const float2*)(g + t * 2);
    float2 bv = *(const float2*)(b + t * 2);
    float2 out;
    out.x = (v0 - mu) * inv * gv.x + bv.x;
    out.y = (v1 - mu) * inv * gv.y + bv.y;
    *(float2*)(y + (size_t)row * H + t * 2) = out;
}

// ---------------------------------------------------------------------------
// 512-thread GEMM mainloop: C[BM x BN] tile of A[M,K]@W[N,K]^T.
// 8 waves (2 wm x 4 wn), per-wave (BM/2)x(BN/4) = MI x NI 16x16 frags.
// ---------------------------------------------------------------------------
template<int BM, int BN, int MI, int NI>
__device__ inline void gemm_mainloop512(const bf16* __restrict__ A,
                                        const bf16* __restrict__ W,
                                        int bm, int bn,
                                        bf16* As, bf16* Bs, f32x4 acc[MI][NI]) {
    int t = threadIdx.x;
    int lane = t & 63, wid = t >> 6;     // 8 waves
    int quad = lane >> 4, n = lane & 15;
    int wm = wid & 1, wn = wid >> 1;     // 2 x 4 wave grid
    int sw = (n & 7) * 8;                // frag-read xor (row&7)*8, row%8==n%8
    int srow = lane >> 3;                // staging: row within 8-row chunk
    int scol = (lane & 7) * 8;           // staging: col base (elems)
    constexpr int APW = BM / 64;         // A 8-row chunks per wave
    constexpr int BPW = BN / 64;
    constexpr int RM = MI * 16;          // rows per wm step
    constexpr int RN = NI * 16;          // cols per wn step
    for (int kt = 0; kt < K; kt += 64) {
        __syncthreads();                 // prior tile's readers done
        #pragma unroll
        for (int i = 0; i < APW; i++) {
            int chunk = wid * APW + i;   // wave-uniform
            int row = chunk * 8 + srow;
            int csrc = scol ^ ((row & 7) * 8);
            __builtin_amdgcn_global_load_lds(
                (g_void*)&A[(size_t)(bm + row) * K + kt + csrc],
                (l_void*)&As[chunk * 512], 16, 0, 0);
        }
        #pragma unroll
        for (int i = 0; i < BPW; i++) {
            int chunk = wid * BPW + i;
            int row = chunk * 8 + srow;
            int csrc = scol ^ ((row & 7) * 8);
            __builtin_amdgcn_global_load_lds(
                (g_void*)&W[(size_t)(bn + row) * K + kt + csrc],
                (l_void*)&Bs[chunk * 512], 16, 0, 0);
        }
        __syncthreads();                 // drains vmcnt(0) before compute
        #pragma unroll
        for (int half = 0; half < 2; half++) {
            bf16x8 af[MI], bfr[NI];
            int c = (half * 32 + quad * 8) ^ sw;
            #pragma unroll
            for (int mi = 0; mi < MI; mi++)
                af[mi] = *(const bf16x8*)&As[(wm * RM + mi * 16 + n) * 64 + c];
            #pragma unroll
            for (int ni = 0; ni < NI; ni++)
                bfr[ni] = *(const bf16x8*)&Bs[(wn * RN + ni * 16 + n) * 64 + c];
            #pragma unroll
            for (int mi = 0; mi < MI; mi++)
                #pragma unroll
                for (int ni = 0; ni < NI; ni++)
                    acc[mi][ni] = __builtin_amdgcn_mfma_f32_16x16x32_bf16(
                        af[mi], bfr[ni], acc[mi][ni], 0, 0, 0);
        }
    }
}

// QKV projection (R7 proven config). grid = (M/128, H/128, 3), 512 thr.
// z=0:q (QSCALE), z=1:k ([B,NH,S,DH]), z=2: v^T [B,NH,DH,S] via LDS transpose.
// R13 lesson: z-merged 1024-thr variant NaN'd; this z-split config is the
// verified local optimum (R8 BM=64 and R12 BM=32 both regressed on W traffic).
__global__ __launch_bounds__(512, 4) void gemm_qkv(
    const bf16* __restrict__ h, const bf16* __restrict__ wb,
    const float* __restrict__ bq, const float* __restrict__ bk,
    const float* __restrict__ bv,
    bf16* __restrict__ qd, bf16* __restrict__ kd, bf16* __restrict__ vtd) {
    __shared__ alignas(16) bf16 smem[17408];   // 34.8KB: As+Bs | T[128][136]
    bf16* As = smem;
    bf16* Bs = smem + 8192;
    int bm = blockIdx.x * 128, bn = blockIdx.y * 128, z = blockIdx.z;
    const bf16* W = wb + (size_t)z * WELEM;
    const float* bias = (z == 0) ? bq : (z == 1) ? bk : bv;
    f32x4 acc[4][2];
    for (int mi = 0; mi < 4; mi++)
        for (int ni = 0; ni < 2; ni++)
            for (int r = 0; r < 4; r++) acc[mi][ni][r] = 0.0f;
    gemm_mainloop512<128, 128, 4, 2>(h, W, bm, bn, As, Bs, acc);
    int t = threadIdx.x;
    int lane = t & 63, wid = t >> 6;
    int quad = lane >> 4, n = lane & 15;
    int wm = wid & 1, wn = wid >> 1;
    if (z < 2) {
        bf16* dst = (z == 0) ? qd : kd;
        for (int mi = 0; mi < 4; mi++)
            for (int ni = 0; ni < 2; ni++)
                for (int r = 0; r < 4; r++) {
                    int i = bm + wm * 64 + mi * 16 + quad * 4 + r;
                    int j = bn + wn * 32 + ni * 16 + n;
                    float val = acc[mi][ni][r] + bias[j];
                    if (z == 0) val *= QSCALE;
                    int b = i >> 11, srow = i & (S - 1);
                    int nh = j >> 6, d = j & (DH - 1);
                    dst[(((size_t)(b * NH + nh)) * S + srow) * DH + d] = (bf16)val;
                }
    } else {
        __syncthreads();                 // all waves done reading As/Bs
        bf16* T = smem;                  // [128 j][136] transposed tile
        for (int mi = 0; mi < 4; mi++)
            for (int ni = 0; ni < 2; ni++)
                for (int r = 0; r < 4; r++) {
                    int il = wm * 64 + mi * 16 + quad * 4 + r;
                    int jl = wn * 32 + ni * 16 + n;
                    float val = acc[mi][ni][r] + bias[bn + jl];
                    T[jl * 136 + il] = (bf16)val;
                }
        __syncthreads();
        int b = bm >> 11, srow0 = bm & (S - 1);
        int c16 = t & 15;                // 16B chunk within d-row
        #pragma unroll
        for (int p = 0; p < 4; p++) {
            int jl = (t >> 4) + p * 32;
            int j = bn + jl;
            int nh = j >> 6, d = j & (DH - 1);
            bf16x8 v = *(const bf16x8*)&T[jl * 136 + c16 * 8];
            *(bf16x8*)&vtd[(((size_t)(b * NH + nh)) * DH + d) * S
                           + srow0 + c16 * 8] = v;
        }
    }
}

// Output projection + bias + residual(h) -> tmp (bf16, row-major [M,H]).
// BM=64 x BN=128, 512 thr, grid (128,4)=512 blocks = 1 exact pass.
__global__ __launch_bounds__(512, 4) void gemm_out(
    const bf16* __restrict__ ctx, const bf16* __restrict__ wo,
    const float* __restrict__ bo, const bf16* __restrict__ resid,
    bf16* __restrict__ dst) {
    __shared__ alignas(16) bf16 As[64 * 64];
    __shared__ alignas(16) bf16 Bs[128 * 64];
    int bm = blockIdx.x * 64, bn = blockIdx.y * 128;
    f32x4 acc[2][2];
    for (int mi = 0; mi < 2; mi++)
        for (int ni = 0; ni < 2; ni++)
            for (int r = 0; r < 4; r++) acc[mi][ni][r] = 0.0f;
    gemm_mainloop512<64, 128, 2, 2>(ctx, wo, bm, bn, As, Bs, acc);
    int lane = threadIdx.x & 63, wid = threadIdx.x >> 6;
    int quad = lane >> 4, n = lane & 15;
    int wm = wid & 1, wn = wid >> 1;
    for (int mi = 0; mi < 2; mi++)
        for (int ni = 0; ni < 2; ni++)
            for (int r = 0; r < 4; r++) {
                int i = bm + wm * 32 + mi * 16 + quad * 4 + r;
                int j = bn + wn * 32 + ni * 16 + n;
                float val = acc[mi][ni][r] + bo[j]
                          + (float)resid[(size_t)i * H + j];
                dst[(size_t)i * H + j] = (bf16)val;
            }
}

// ---------------------------------------------------------------------------
// Flash attention v10 (PROVEN 57.5-58.3us — R8/R10/R12): key-split waves +
// T14 reg-staged pipelined K/V. 512 thr = 8 waves = 4 q-groups x 2 key-
// halves; each wave 32 q x 64 keys. Next tile's K/V loads issue right after
// the write-barrier, hiding HBM/L2 latency under a full iter of compute.
// R11 lesson: LDS staging is load-bearing for COALESCING (direct-global
// fragment reads shatter into 16 segments/inst -> 2.3x slower).
// O,l are pure sums over keys (exp2 softmax); key-half partials combine
// once in the epilogue via LDS.
// LDS: Ks 16KB + Vs 16KB + Ps 8x4.5KB = 68KB -> 2 blocks/CU (16 waves).
// ---------------------------------------------------------------------------
constexpr int LDP9 = 72;    // P row stride (64 + 8 pad)

#if __has_builtin(__builtin_amdgcn_exp2f)
#define EXP2(x) __builtin_amdgcn_exp2f(x)
#else
#define EXP2(x) exp2f(x)
#endif

__global__ __launch_bounds__(512, 4) void attn_kernel(
    const bf16* __restrict__ q, const bf16* __restrict__ k,
    const bf16* __restrict__ vt, const float* __restrict__ mask2,
    bf16* __restrict__ ctx) {
    int bh = blockIdx.y;                 // b*NH + nh
    int b = bh >> 3, nh = bh & 7;
    int t = threadIdx.x, wid = t >> 6, lane = t & 63;
    int quad = lane >> 4, n = lane & 15;
    int qg = wid >> 1, kh = wid & 1;     // q-group, key-half
    int qbase = blockIdx.x * 128 + qg * 32;
    int kO = kh * 64;                    // this wave's key offset in tile

    const bf16* Qp = q  + (size_t)bh * S * DH;
    const bf16* Kp = k  + (size_t)bh * S * DH;
    const bf16* Vt = vt + (size_t)bh * DH * S;
    const float* mrow = mask2 + (size_t)b * S;   // pre-scaled by log2e

    __shared__ alignas(16) bf16 smem[34816];     // 68KB
    bf16* Ks = smem;                     // [128 keys][64 d], swizzled
    bf16* Vs = smem + 8192;              // [64 d][128 keys], swizzled
    bf16* Pw = smem + 16384 + wid * (32 * LDP9); // per-wave P^T [q][key]

    int sw = (n & 7) * 8;                // frag-read xor

    // per-thread staging geometry (K: 512x16B units; V: 1024x16B units)
    int krow = t >> 3;
    int kcs  = ((t & 7) * 8) ^ ((krow & 7) * 8);     // swizzled col
    size_t koff = (size_t)krow * DH + kcs;           // + kb*DH per tile
    int vr0 = t >> 4,        vc0 = ((t & 15) * 8) ^ ((vr0 & 7) * 8);
    int vr1 = (t + 512) >> 4, vc1 = ((t & 15) * 8) ^ ((vr1 & 7) * 8);
    size_t voff0 = (size_t)vr0 * S + vc0;            // + kb per tile
    size_t voff1 = (size_t)vr1 * S + vc1;

    bf16x8 qf[2][2];
    #pragma unroll
    for (int qt = 0; qt < 2; qt++)
        #pragma unroll
        for (int hh = 0; hh < 2; hh++)
            qf[qt][hh] = *(const bf16x8*)
                &Qp[(size_t)(qbase + qt * 16 + n) * DH + hh * 32 + quad * 8];

    f32x4 O[2][4];
    #pragma unroll
    for (int qt = 0; qt < 2; qt++)
        for (int i = 0; i < 4; i++)
            for (int r = 0; r < 4; r++) O[qt][i][r] = 0.0f;
    float l_run[2] = {0.0f, 0.0f};

    // prologue: load tile 0 into regs
    uint4 kreg  = *(const uint4*)&Kp[koff];
    uint4 vreg0 = *(const uint4*)&Vt[voff0];
    uint4 vreg1 = *(const uint4*)&Vt[voff1];

    for (int kb = 0; kb < S; kb += 128) {
        __syncthreads();                 // prior tile's readers done
        *(uint4*)&Ks[(size_t)t * 8] = kreg;
        *(uint4*)&Vs[(size_t)t * 8] = vreg0;
        *(uint4*)&Vs[(size_t)(t + 512) * 8] = vreg1;
        __syncthreads();                 // tile visible to all waves

        if (kb + 128 < S) {              // issue next-tile loads; latency
            kreg  = *(const uint4*)&Kp[koff + (size_t)(kb + 128) * DH];
            vreg0 = *(const uint4*)&Vt[voff0 + (kb + 128)];
            vreg1 = *(const uint4*)&Vt[voff1 + (kb + 128)];
        }                                // hides under this iter's compute

        #pragma unroll
        for (int kt = 0; kt < 4; kt++) { // this wave's 64-key half
            const bf16* kr = &Ks[(kO + kt * 16 + n) * 64];
            bf16x8 ka = *(const bf16x8*)&kr[(quad * 8) ^ sw];
            bf16x8 kc = *(const bf16x8*)&kr[(32 + quad * 8) ^ sw];
            float4 mk = *(const float4*)&mrow[kb + kO + kt * 16 + quad * 4];
            #pragma unroll
            for (int qt = 0; qt < 2; qt++) {
                f32x4 s;
                for (int r = 0; r < 4; r++) s[r] = 0.0f;
                s = __builtin_amdgcn_mfma_f32_16x16x32_bf16(ka, qf[qt][0], s, 0, 0, 0);
                s = __builtin_amdgcn_mfma_f32_16x16x32_bf16(kc, qf[qt][1], s, 0, 0, 0);
                float p0 = EXP2(s[0] + mk.x);
                float p1 = EXP2(s[1] + mk.y);
                float p2 = EXP2(s[2] + mk.z);
                float p3 = EXP2(s[3] + mk.w);
                l_run[qt] += (p0 + p1) + (p2 + p3);
                bf16x4 w;
                w[0] = (bf16)p0; w[1] = (bf16)p1; w[2] = (bf16)p2; w[3] = (bf16)p3;
                *(bf16x4*)&Pw[(qt * 16 + n) * LDP9 + kt * 16 + quad * 4] = w;
            }
        }

        __builtin_amdgcn_s_setprio(1);
        #pragma unroll
        for (int ks = 0; ks < 2; ks++)
            #pragma unroll
            for (int qt = 0; qt < 2; qt++) {
                bf16x8 pf = *(const bf16x8*)
                    &Pw[(qt * 16 + n) * LDP9 + ks * 32 + quad * 8];
                #pragma unroll
                for (int dt = 0; dt < 4; dt++) {
                    bf16x8 vf = *(const bf16x8*)
                        &Vs[(dt * 16 + n) * 128 + ((kO + ks * 32 + quad * 8) ^ sw)];
                    O[qt][dt] = __builtin_amdgcn_mfma_f32_16x16x32_bf16(
                        vf, pf, O[qt][dt], 0, 0, 0);
                }
            }
        __builtin_amdgcn_s_setprio(0);
    }

    // --- combine key-half partials (O,l are pure sums) -------------------
    float* Ob = (float*)smem;            // [4 qg][32 q][68] fp32 (2-way banks)
    float* Lb = Ob + 4 * 32 * 68;        // [4 qg][2 qt][64 lanes]
    __syncthreads();                     // all compute done; smem reusable
    if (kh) {
        #pragma unroll
        for (int qt = 0; qt < 2; qt++) {
            #pragma unroll
            for (int dt = 0; dt < 4; dt++)
                *(f32x4*)&Ob[(qg * 32 + qt * 16 + n) * 68 + dt * 16 + quad * 4]
                    = O[qt][dt];
            Lb[(qg * 2 + qt) * 64 + lane] = l_run[qt];
        }
    }
    __syncthreads();
    if (!kh) {
        #pragma unroll
        for (int qt = 0; qt < 2; qt++) {
            float l = l_run[qt] + Lb[(qg * 2 + qt) * 64 + lane];
            l += __shfl_xor(l, 16, 64);
            l += __shfl_xor(l, 32, 64);
            float linv = 1.0f / l;
            int srow = qbase + qt * 16 + n;
            #pragma unroll
            for (int dt = 0; dt < 4; dt++) {
                f32x4 po = *(const f32x4*)
                    &Ob[(qg * 32 + qt * 16 + n) * 68 + dt * 16 + quad * 4];
                bf16x4 o4;
                for (int r = 0; r < 4; r++)
                    o4[r] = (bf16)((O[qt][dt][r] + po[r]) * linv);
                int col = nh * 64 + dt * 16 + quad * 4;
                *(bf16x4*)&ctx[((size_t)(b * S + srow)) * H + col] = o4;
            }
        }
    }
}

// ---------------------------------------------------------------------------
extern "C" void kernel_launch(void* const* d_in, const int* in_sizes, int n_in,
                              void* d_out, int out_size, void* d_ws, size_t ws_size,
                              hipStream_t stream) {
    const float* hidden = (const float*)d_in[0];
    const float* mask   = (const float*)d_in[1];
    const float* ln1_g  = (const float*)d_in[2];
    const float* ln1_b  = (const float*)d_in[3];
    const float* wq = (const float*)d_in[4],  *bq = (const float*)d_in[5];
    const float* wk = (const float*)d_in[6],  *bk = (const float*)d_in[7];
    const float* wv = (const float*)d_in[8],  *bv = (const float*)d_in[9];
    const float* wo = (const float*)d_in[10], *bo = (const float*)d_in[11];
    const float* ln2_g = (const float*)d_in[12];
    const float* ln2_b = (const float*)d_in[13];

    const size_t T = (size_t)M * H;     // 4M elems per activation tensor
    bf16* wb  = (bf16*)d_ws;            // 4 weights, bf16: 4*WELEM
    bf16* h   = wb  + (size_t)4 * WELEM;
    bf16* qd  = h   + T;
    bf16* kd  = qd  + T;
    bf16* vtd = kd  + T;
    bf16* ctx = vtd + T;
    float* mask2 = (float*)(ctx + T);   // B*S fp32, mask*log2e
    bf16* tmp = qd;                     // qd is dead after attn_kernel

    prep<<<M + 1024 + 32, 256, 0, stream>>>(
        hidden, ln1_g, ln1_b, wq, wk, wv, wo, mask, h, wb, mask2);
    gemm_qkv<<<dim3(M / 128, H / 128, 3), 512, 0, stream>>>(
        h, wb, bq, bk, bv, qd, kd, vtd);
    attn_kernel<<<dim3(S / 128, Bsz * NH), 512, 0, stream>>>(qd, kd, vtd, mask2, ctx);
    gemm_out<<<dim3(M / 64, H / 128), 512, 0, stream>>>(
        ctx, wb + (size_t)3 * WELEM, bo, h, tmp);
    ln_bf16_f32<<<M, 256, 0, stream>>>(tmp, ln2_g, ln2_b, (float*)d_out);
}